// Round 4
// baseline (147.982 us; speedup 1.0000x reference)
//
#include <hip/hip_runtime.h>

// Kernel 1: per-block partial sums of squared differences.
// n4 = 4,192,256 float4 pairs = 2047 blocks x 256 threads x 8 pairs EXACTLY
// (2047*2048 = 4,192,256) -> no bounds checks, no OOB.
//
// MLP fix, take 4: rounds 1-2 (inline-asm operand barrier) failed to build;
// round 3 (__syncthreads fence) was legally optimized around — LLVM sank the
// read-only loads past the barrier, VGPR stayed 32, perf unchanged. The
// pre-RA scheduler's register-pressure heuristic is what collapses the load
// pipeline to depth ~2-4; the documented override is sched_group_barrier
// (T19; compiles + applies on gfx950 per m137). We request one scheduling
// group of 16 VMEM_READ (mask 0x20) followed by the VALU cluster (0x2):
// 16 global_load_dwordx4 back-to-back => 16 KB in flight per wave, waitcnt
// pipelined (first use waits vmcnt(14), not vmcnt(0)).
// __launch_bounds__(256,4): 128-VGPR budget — room for 64 payload VGPRs.
__global__ __launch_bounds__(256, 4) void ssd_partials(const float4* __restrict__ p,
                                                       const float4* __restrict__ t,
                                                       float* __restrict__ ws) {
    const int tid = threadIdx.x;
    // Each block covers 2048 consecutive float4s.
    const long long base = (long long)blockIdx.x * 2048 + tid;

    float4 a[8], b[8];
    #pragma unroll
    for (int u = 0; u < 8; ++u) a[u] = p[base + u * 256];
    #pragma unroll
    for (int u = 0; u < 8; ++u) b[u] = t[base + u * 256];

    // Scheduler directive, not a memory fence: emit 16 VMEM_READs first,
    // then the VALU block. Overrides the pressure-driven interleave that
    // collapsed this to ~4 loads in flight (VGPR=32) in every prior build.
    __builtin_amdgcn_sched_group_barrier(0x020, 16, 0);  // 16x VMEM_READ
    __builtin_amdgcn_sched_group_barrier(0x002, 64, 0);  // then VALU cluster

    float acc0 = 0.f, acc1 = 0.f, acc2 = 0.f, acc3 = 0.f;
    #pragma unroll
    for (int u = 0; u < 8; ++u) {
        float dx = a[u].x - b[u].x; acc0 += dx * dx;
        float dy = a[u].y - b[u].y; acc1 += dy * dy;
        float dz = a[u].z - b[u].z; acc2 += dz * dz;
        float dw = a[u].w - b[u].w; acc3 += dw * dw;
    }
    float acc = (acc0 + acc1) + (acc2 + acc3);

    // wave-64 reduce
    #pragma unroll
    for (int off = 32; off > 0; off >>= 1)
        acc += __shfl_down(acc, off, 64);

    __shared__ float wave_sums[4];
    const int lane = tid & 63;
    const int wave = tid >> 6;
    if (lane == 0) wave_sums[wave] = acc;
    __syncthreads();

    if (tid == 0)
        ws[blockIdx.x] = (wave_sums[0] + wave_sums[1]) + (wave_sums[2] + wave_sums[3]);
}

// Kernel 2: reduce 2047 partials -> out[0] = sum * scale.
// Single block of 256; every ws slot read was written by kernel 1.
// Deterministic read order => bit-exact across runs.
__global__ __launch_bounds__(256) void ssd_finalize(const float* __restrict__ ws,
                                                    float* __restrict__ out,
                                                    float scale) {
    const int tid = threadIdx.x;
    float acc = 0.f;
    #pragma unroll
    for (int k = 0; k < 8; ++k) {
        int idx = tid + k * 256;
        if (idx < 2047) acc += ws[idx];
    }

    #pragma unroll
    for (int off = 32; off > 0; off >>= 1)
        acc += __shfl_down(acc, off, 64);

    __shared__ float wave_sums[4];
    const int lane = tid & 63;
    const int wave = tid >> 6;
    if (lane == 0) wave_sums[wave] = acc;
    __syncthreads();

    if (tid == 0)
        out[0] = ((wave_sums[0] + wave_sums[1]) + (wave_sums[2] + wave_sums[3])) * scale;
}

extern "C" void kernel_launch(void* const* d_in, const int* in_sizes, int n_in,
                              void* d_out, int out_size, void* d_ws, size_t ws_size,
                              hipStream_t stream) {
    const float* pred = (const float*)d_in[0];
    const float* targ = (const float*)d_in[1];
    float* out = (float*)d_out;
    float* ws = (float*)d_ws;  // needs 2047 floats = 8188 B

    const int B = 4096;
    const int S = 2047;  // 2*d+1 with d=1023 — slice covers the whole tensor
    const float scale = 1.0f / ((float)S * (float)B);
    // total float4 pairs = B*S*2/4 = 4,192,256 = 2047 * 2048 exactly.

    ssd_partials<<<2047, 256, 0, stream>>>((const float4*)pred,
                                           (const float4*)targ, ws);
    ssd_finalize<<<1, 256, 0, stream>>>(ws, out, scale);
}